// Round 1
// baseline (131.686 us; speedup 1.0000x reference)
//
#include <hip/hip_runtime.h>
#include <hip/hip_bf16.h>

typedef __attribute__((ext_vector_type(8))) _Float16 f16x8;
typedef __attribute__((ext_vector_type(4))) float f32x4;

#define B_ 8
#define N_ 4096
#define C_ 64
#define CQ_ 32

// ---------------- projection kernel: q,k,v (fp16) + |q|^2,|k|^2 (f32) ----------------
__global__ __launch_bounds__(256) void proj_kernel(
    const float* __restrict__ x,
    const float* __restrict__ Wq, const float* __restrict__ bq,
    const float* __restrict__ Wk, const float* __restrict__ bk,
    const float* __restrict__ Wv, const float* __restrict__ bv,
    _Float16* __restrict__ qh, _Float16* __restrict__ kh,
    _Float16* __restrict__ vh,
    float* __restrict__ qsq, float* __restrict__ ksq)
{
    __shared__ __align__(16) float sWqT[64][32]; // [c][o]
    __shared__ __align__(16) float sWkT[64][32];
    __shared__ __align__(16) float sWvT[64][64];
    __shared__ float sb[128];
    const int t = threadIdx.x;
    for (int i = t; i < 2048; i += 256) {
        int o = i >> 6, c = i & 63;
        sWqT[c][o] = Wq[i];
        sWkT[c][o] = Wk[i];
    }
    for (int i = t; i < 4096; i += 256) {
        int o = i >> 6, c = i & 63;
        sWvT[c][o] = Wv[i];
    }
    if (t < 32) { sb[t] = bq[t]; sb[32 + t] = bk[t]; }
    if (t < 64) { sb[64 + t] = bv[t]; }
    __syncthreads();

    const int gid = blockIdx.x * 256 + t;
    const int b = gid >> 12;
    const int n = gid & (N_ - 1);
    const float* xp = x + (size_t)b * C_ * N_ + n;

    // ---- q / k ----
    float q[32], k[32];
    #pragma unroll
    for (int o = 0; o < 32; ++o) { q[o] = sb[o]; k[o] = sb[32 + o]; }
    #pragma unroll 4
    for (int c = 0; c < 64; ++c) {
        float xc = xp[(size_t)c * N_];
        #pragma unroll
        for (int j = 0; j < 8; ++j) {
            f32x4 wq = *(const f32x4*)&sWqT[c][j * 4];
            f32x4 wk = *(const f32x4*)&sWkT[c][j * 4];
            #pragma unroll
            for (int e = 0; e < 4; ++e) {
                q[j * 4 + e] = fmaf(wq[e], xc, q[j * 4 + e]);
                k[j * 4 + e] = fmaf(wk[e], xc, k[j * 4 + e]);
            }
        }
    }
    float qs = 0.f, kss = 0.f;
    _Float16* qrow = qh + ((size_t)b * N_ + n) * CQ_;
    _Float16* krow = kh + ((size_t)b * N_ + n) * CQ_;
    #pragma unroll
    for (int o = 0; o < 32; ++o) {
        qs = fmaf(q[o], q[o], qs);
        kss = fmaf(k[o], k[o], kss);
        qrow[o] = (_Float16)q[o];
        krow[o] = (_Float16)k[o];
    }
    qsq[(size_t)b * N_ + n] = qs;
    ksq[(size_t)b * N_ + n] = kss;

    // ---- v ----
    float v[64];
    #pragma unroll
    for (int o = 0; o < 64; ++o) v[o] = sb[64 + o];
    #pragma unroll 4
    for (int c = 0; c < 64; ++c) {
        float xc = xp[(size_t)c * N_];
        #pragma unroll
        for (int j = 0; j < 16; ++j) {
            f32x4 wv = *(const f32x4*)&sWvT[c][j * 4];
            #pragma unroll
            for (int e = 0; e < 4; ++e) v[j * 4 + e] = fmaf(wv[e], xc, v[j * 4 + e]);
        }
    }
    #pragma unroll
    for (int o = 0; o < 64; ++o)
        vh[((size_t)b * C_ + o) * N_ + n] = (_Float16)v[o];
}

// ---------------- fused RBF-attention kernel ----------------
// grid: B * (N/64) blocks, 256 threads (4 waves); wave w owns 16 query rows.
// Single pass over keys (no online max needed: similarity in (0,1]).
#define MB 128
__global__ __launch_bounds__(256) void attn_kernel(
    const float* __restrict__ x,
    const _Float16* __restrict__ qh,
    const _Float16* __restrict__ kh,
    const _Float16* __restrict__ vh,
    const float* __restrict__ qsq,
    const float* __restrict__ ksq,
    const float* __restrict__ sigp,
    float* __restrict__ out)
{
    __shared__ __align__(16) _Float16 Ks[MB][32];       // keys x qk-channels
    __shared__ __align__(16) _Float16 Vs[64][MB + 8];   // v-channels x keys (transposed), pad: stride 272B
    __shared__ __align__(16) _Float16 Ps[4][16][MB + 8];// per-wave attention weights
    __shared__ float sKsq[MB];

    const int t = threadIdx.x;
    const int w = t >> 6;
    const int l = t & 63;
    const int lg = l >> 4;   // 16-lane group 0..3
    const int lm = l & 15;

    const int b = blockIdx.x >> 6;
    const int qblk = blockIdx.x & 63;
    const int q0 = qblk * 64 + w * 16;

    const float sv = *sigp;
    const float cdist = 1.0f / (2.0f * sv * sv);

    // Q fragment: row = lm, channels 8*lg..8*lg+7 (consistent k-map on both operands)
    const f16x8 qfrag = *(const f16x8*)(qh + ((size_t)b * N_ + q0 + lm) * CQ_ + 8 * lg);
    float qs[4];
    #pragma unroll
    for (int r = 0; r < 4; ++r) qs[r] = qsq[(size_t)b * N_ + q0 + lg * 4 + r];

    f32x4 acc[4];
    #pragma unroll
    for (int i = 0; i < 4; ++i) acc[i] = (f32x4){0.f, 0.f, 0.f, 0.f};
    float denom[4] = {0.f, 0.f, 0.f, 0.f};

    for (int m0 = 0; m0 < N_; m0 += MB) {
        // ---- stage K (row-major), V (transposed), ksq into LDS ----
        #pragma unroll
        for (int rep = 0; rep < 2; ++rep) {
            const int idx = rep * 256 + t;
            const int row = idx >> 2, c4 = idx & 3;
            *(f32x4*)(&Ks[row][c4 * 8]) =
                *(const f32x4*)(kh + ((size_t)b * N_ + m0 + row) * CQ_ + c4 * 8);
        }
        if (t < MB) sKsq[t] = ksq[(size_t)b * N_ + m0 + t];
        #pragma unroll
        for (int rep = 0; rep < 4; ++rep) {
            const int idx = rep * 256 + t;
            const int vr = idx >> 4, vc = idx & 15;
            *(f32x4*)(&Vs[vr][vc * 8]) =
                *(const f32x4*)(vh + ((size_t)b * C_ + vr) * N_ + m0 + vc * 8);
        }
        __syncthreads();

        // ---- S = Q K^T  (D: row=query=(lg*4+r), col=key=lm+16*tm) ----
        f32x4 S[MB / 16];
        #pragma unroll
        for (int tm = 0; tm < MB / 16; ++tm) {
            const f16x8 kf = *(const f16x8*)(&Ks[tm * 16 + lm][8 * lg]);
            S[tm] = __builtin_amdgcn_mfma_f32_16x16x32_f16(
                qfrag, kf, (f32x4){0.f, 0.f, 0.f, 0.f}, 0, 0, 0);
        }
        // ---- w = exp(exp(-dist/(2sigma^2))); accumulate denom; write P ----
        #pragma unroll
        for (int tm = 0; tm < MB / 16; ++tm) {
            const float kq = sKsq[tm * 16 + lm];
            #pragma unroll
            for (int r = 0; r < 4; ++r) {
                const float dist = qs[r] + kq - 2.0f * S[tm][r];
                const float sim = __expf(-dist * cdist);
                const float wg = __expf(sim);
                denom[r] += wg;
                Ps[w][lg * 4 + r][tm * 16 + lm] = (_Float16)wg;
            }
        }
        asm volatile("s_waitcnt lgkmcnt(0)" ::: "memory"); // P writes visible to own wave's reads
        // ---- O += P V  (A=P rows=query, B=V cols=channel, K=keys) ----
        #pragma unroll
        for (int ks = 0; ks < MB / 32; ++ks) {
            const f16x8 pf = *(const f16x8*)(&Ps[w][lm][ks * 32 + 8 * lg]);
            #pragma unroll
            for (int tc = 0; tc < 4; ++tc) {
                const f16x8 vf = *(const f16x8*)(&Vs[tc * 16 + lm][ks * 32 + 8 * lg]);
                acc[tc] = __builtin_amdgcn_mfma_f32_16x16x32_f16(pf, vf, acc[tc], 0, 0, 0);
            }
        }
        __syncthreads();
    }

    // ---- row-sum reduce denom across the 16-lane group ----
    #pragma unroll
    for (int r = 0; r < 4; ++r) {
        float d = denom[r];
        d += __shfl_xor(d, 1);
        d += __shfl_xor(d, 2);
        d += __shfl_xor(d, 4);
        d += __shfl_xor(d, 8);
        denom[r] = 1.0f / d;
    }
    // ---- epilogue: out[b, n, c] = x_flat + O/denom (raw-reshape identity) ----
    #pragma unroll
    for (int tc = 0; tc < 4; ++tc) {
        #pragma unroll
        for (int r = 0; r < 4; ++r) {
            const size_t idx = (size_t)b * N_ * C_ + (size_t)(q0 + lg * 4 + r) * C_ + tc * 16 + lm;
            out[idx] = x[idx] + acc[tc][r] * denom[r];
        }
    }
}

extern "C" void kernel_launch(void* const* d_in, const int* in_sizes, int n_in,
                              void* d_out, int out_size, void* d_ws, size_t ws_size,
                              hipStream_t stream) {
    const float* x   = (const float*)d_in[0];
    const float* Wq  = (const float*)d_in[1];
    const float* bq  = (const float*)d_in[2];
    const float* Wk  = (const float*)d_in[3];
    const float* bk  = (const float*)d_in[4];
    const float* Wv  = (const float*)d_in[5];
    const float* bv  = (const float*)d_in[6];
    const float* sig = (const float*)d_in[7];
    float* out = (float*)d_out;

    char* ws = (char*)d_ws;
    _Float16* qh = (_Float16*)(ws);                       // 2 MB  [B][N][32]
    _Float16* kh = (_Float16*)(ws + (2u << 20));          // 2 MB  [B][N][32]
    _Float16* vh = (_Float16*)(ws + (4u << 20));          // 4 MB  [B][64][N]
    float*   qsq = (float*)(ws + (8u << 20));             // 128 KB [B][N]
    float*   ksq = (float*)(ws + (8u << 20) + (128u << 10)); // 128 KB

    proj_kernel<<<(B_ * N_) / 256, 256, 0, stream>>>(x, Wq, bq, Wk, bk, Wv, bv,
                                                     qh, kh, vh, qsq, ksq);
    attn_kernel<<<B_ * (N_ / 64), 256, 0, stream>>>(x, qh, kh, vh, qsq, ksq, sig, out);
}

// Round 2
// 101.228 us; speedup vs baseline: 1.3009x; 1.3009x over previous
//
#include <hip/hip_runtime.h>
#include <hip/hip_bf16.h>

typedef __attribute__((ext_vector_type(8))) _Float16 f16x8;
typedef __attribute__((ext_vector_type(4))) float f32x4;

#define B_ 8
#define N_ 4096
#define C_ 64
#define CQ_ 32

// log2(e) and log2(log2(e))
#define L2E_ 1.4426950408889634f
#define LOG2L_ 0.5287663729448977f

// ---------------- projection kernel v2: role-split, scalar weights ----------------
// grid: B * (N/64) = 512 blocks, 256 threads. wave = role (q | k | v-lo | v-hi),
// lane = pixel. x column in VGPRs, weights via wave-uniform s_loads.
// Stores q,k,v in fp16 + PRE-SCALED norms: qsq2 = |q|^2*cd*L - log2L, ksq2 = |k|^2*cd*L.
__global__ __launch_bounds__(256) void proj_kernel(
    const float* __restrict__ x,
    const float* __restrict__ Wq, const float* __restrict__ bq,
    const float* __restrict__ Wk, const float* __restrict__ bk,
    const float* __restrict__ Wv, const float* __restrict__ bv,
    const float* __restrict__ sigp,
    _Float16* __restrict__ qh, _Float16* __restrict__ kh,
    _Float16* __restrict__ vh,
    float* __restrict__ qsq2, float* __restrict__ ksq2)
{
    const int t = threadIdx.x;
    const int role = __builtin_amdgcn_readfirstlane(t >> 6);
    const int l = t & 63;
    const int b = blockIdx.x >> 6;
    const int n = (blockIdx.x & 63) * 64 + l;

    // ---- x column (64 channels of this pixel) into registers ----
    float xr[64];
    const float* xp = x + (size_t)b * C_ * N_ + n;
    #pragma unroll
    for (int c = 0; c < 64; ++c) xr[c] = xp[(size_t)c * N_];

    // ---- role-specific weight/bias base (wave-uniform -> s_load path) ----
    const float* Wr = (role == 0) ? Wq : (role == 1) ? Wk : (role == 2) ? Wv : (Wv + 32 * 64);
    const float* br = (role == 0) ? bq : (role == 1) ? bk : (role == 2) ? bv : (bv + 32);

    float acc[32];
    #pragma unroll
    for (int o = 0; o < 32; ++o) acc[o] = br[o];

    // c-tiled so weight s_loads merge into wide s_load_dwordx8
    #pragma unroll
    for (int c0 = 0; c0 < 64; c0 += 8) {
        #pragma unroll
        for (int o = 0; o < 32; ++o) {
            #pragma unroll
            for (int dc = 0; dc < 8; ++dc)
                acc[o] = fmaf(Wr[o * 64 + c0 + dc], xr[c0 + dc], acc[o]);
        }
    }

    const float sv = sigp[0];
    const float cdL = 0.7213475204444817f / (sv * sv);  // L2E/2 / sigma^2

    if (role < 2) {
        float s = 0.f;
        #pragma unroll
        for (int o = 0; o < 32; ++o) s = fmaf(acc[o], acc[o], s);
        _Float16* row = (role ? kh : qh) + ((size_t)b * N_ + n) * CQ_;
        #pragma unroll
        for (int j = 0; j < 4; ++j) {
            f16x8 h;
            #pragma unroll
            for (int e = 0; e < 8; ++e) h[e] = (_Float16)acc[j * 8 + e];
            *(f16x8*)(row + j * 8) = h;
        }
        if (role == 0) qsq2[(size_t)b * N_ + n] = s * cdL - LOG2L_;
        else           ksq2[(size_t)b * N_ + n] = s * cdL;
    } else {
        _Float16* vp = vh + ((size_t)b * C_ + (role == 3 ? 32 : 0)) * N_ + n;
        #pragma unroll
        for (int o = 0; o < 32; ++o) vp[(size_t)o * N_] = (_Float16)acc[o];
    }
}

// ---------------- fused RBF-attention kernel v2 ----------------
// grid: B * (N/64) blocks, 256 threads (4 waves); wave owns 16 query rows.
// Double-buffered K/V staging with register prefetch, 1 barrier/tile.
// Postproc: w = exp2(exp2(fma(S, c1, -(qs2+kq2)))) with all scales folded.
#define MB 128
#define KPAD 40
#define VPAD (MB + 8)
__global__ __launch_bounds__(256) void attn_kernel(
    const float* __restrict__ x,
    const _Float16* __restrict__ qh,
    const _Float16* __restrict__ kh,
    const _Float16* __restrict__ vh,
    const float* __restrict__ qsq2,
    const float* __restrict__ ksq2,
    const float* __restrict__ sigp,
    float* __restrict__ out)
{
    __shared__ __align__(16) _Float16 Ks[2][MB][KPAD];
    __shared__ __align__(16) _Float16 Vs[2][64][VPAD];
    __shared__ __align__(16) _Float16 Ps[4][16][VPAD];
    __shared__ float sKsq[2][MB];

    const int t = threadIdx.x;
    const int wid = t >> 6;
    const int l = t & 63;
    const int lg = l >> 4;
    const int lm = l & 15;

    const int b = blockIdx.x >> 6;
    const int q0 = (blockIdx.x & 63) * 64 + wid * 16;

    const float sv = sigp[0];
    const float c1 = L2E_ / (sv * sv);   // 2*cd*log2e

    // Q fragment: row = lm, channels 8*lg..8*lg+7
    const f16x8 qfrag = *(const f16x8*)(qh + ((size_t)b * N_ + q0 + lm) * CQ_ + 8 * lg);
    float qs2[4];
    #pragma unroll
    for (int r = 0; r < 4; ++r) qs2[r] = qsq2[(size_t)b * N_ + q0 + lg * 4 + r];

    // staging addressing (same for every tile)
    const int krow = t >> 2, kc4 = t & 3;          // K: rows 0..63 (+64 on rep1)
    const int vr = t >> 4, vc = t & 15;            // V: rows 0..15 (+16/rep)

    f32x4 kreg[2], vreg[4];
    float ksreg;

    auto LOADT = [&](int m0) {
        #pragma unroll
        for (int rep = 0; rep < 2; ++rep)
            kreg[rep] = *(const f32x4*)(kh + ((size_t)b * N_ + m0 + rep * 64 + krow) * CQ_ + kc4 * 8);
        #pragma unroll
        for (int rep = 0; rep < 4; ++rep)
            vreg[rep] = *(const f32x4*)(vh + ((size_t)b * C_ + rep * 16 + vr) * N_ + m0 + vc * 8);
        if (t < MB) ksreg = ksq2[(size_t)b * N_ + m0 + t];
    };
    auto WRITET = [&](int buf) {
        #pragma unroll
        for (int rep = 0; rep < 2; ++rep)
            *(f32x4*)(&Ks[buf][rep * 64 + krow][kc4 * 8]) = kreg[rep];
        #pragma unroll
        for (int rep = 0; rep < 4; ++rep)
            *(f32x4*)(&Vs[buf][rep * 16 + vr][vc * 8]) = vreg[rep];
        if (t < MB) sKsq[buf][t] = ksreg;
    };

    f32x4 acc[4];
    #pragma unroll
    for (int i = 0; i < 4; ++i) acc[i] = (f32x4){0.f, 0.f, 0.f, 0.f};
    float denom[4] = {0.f, 0.f, 0.f, 0.f};

    LOADT(0);
    WRITET(0);
    __syncthreads();

    const int NT = N_ / MB;
    for (int it = 0; it < NT; ++it) {
        const int buf = it & 1;
        if (it + 1 < NT) LOADT((it + 1) * MB);   // prefetch next tile into regs

        // ---- S = Q K^T ----
        f32x4 S[MB / 16];
        #pragma unroll
        for (int tm = 0; tm < MB / 16; ++tm) {
            const f16x8 kf = *(const f16x8*)(&Ks[buf][tm * 16 + lm][8 * lg]);
            S[tm] = __builtin_amdgcn_mfma_f32_16x16x32_f16(
                qfrag, kf, (f32x4){0.f, 0.f, 0.f, 0.f}, 0, 0, 0);
        }
        // ---- w = exp2(exp2(S*c1 - qs2 - kq2)); denom; P ----
        #pragma unroll
        for (int tm = 0; tm < MB / 16; ++tm) {
            const float kq2 = sKsq[buf][tm * 16 + lm];
            #pragma unroll
            for (int r = 0; r < 4; ++r) {
                const float a = fmaf(S[tm][r], c1, -(qs2[r] + kq2));
                const float sim2 = __builtin_amdgcn_exp2f(a);
                const float wg = __builtin_amdgcn_exp2f(sim2);
                denom[r] += wg;
                Ps[wid][lg * 4 + r][tm * 16 + lm] = (_Float16)wg;
            }
        }
        asm volatile("s_waitcnt lgkmcnt(0)" ::: "memory");
        // ---- O += P V ----
        #pragma unroll
        for (int ks = 0; ks < MB / 32; ++ks) {
            const f16x8 pf = *(const f16x8*)(&Ps[wid][lm][ks * 32 + 8 * lg]);
            #pragma unroll
            for (int tc = 0; tc < 4; ++tc) {
                const f16x8 vf = *(const f16x8*)(&Vs[buf][tc * 16 + lm][ks * 32 + 8 * lg]);
                acc[tc] = __builtin_amdgcn_mfma_f32_16x16x32_f16(pf, vf, acc[tc], 0, 0, 0);
            }
        }
        if (it + 1 < NT) WRITET(buf ^ 1);        // fill alternate buffer
        __syncthreads();                          // one barrier per tile
    }

    // ---- denom reduce across 16-lane group ----
    #pragma unroll
    for (int r = 0; r < 4; ++r) {
        float d = denom[r];
        d += __shfl_xor(d, 1);
        d += __shfl_xor(d, 2);
        d += __shfl_xor(d, 4);
        d += __shfl_xor(d, 8);
        denom[r] = 1.0f / d;
    }
    // ---- epilogue: out = x + O/denom (raw-reshape identity) ----
    #pragma unroll
    for (int tc = 0; tc < 4; ++tc) {
        #pragma unroll
        for (int r = 0; r < 4; ++r) {
            const size_t idx = (size_t)b * N_ * C_ + (size_t)(q0 + lg * 4 + r) * C_ + tc * 16 + lm;
            out[idx] = x[idx] + acc[tc][r] * denom[r];
        }
    }
}

extern "C" void kernel_launch(void* const* d_in, const int* in_sizes, int n_in,
                              void* d_out, int out_size, void* d_ws, size_t ws_size,
                              hipStream_t stream) {
    const float* x   = (const float*)d_in[0];
    const float* Wq  = (const float*)d_in[1];
    const float* bq  = (const float*)d_in[2];
    const float* Wk  = (const float*)d_in[3];
    const float* bk  = (const float*)d_in[4];
    const float* Wv  = (const float*)d_in[5];
    const float* bv  = (const float*)d_in[6];
    const float* sig = (const float*)d_in[7];
    float* out = (float*)d_out;

    char* ws = (char*)d_ws;
    _Float16* qh = (_Float16*)(ws);                          // 2 MB  [B][N][32]
    _Float16* kh = (_Float16*)(ws + (2u << 20));             // 2 MB  [B][N][32]
    _Float16* vh = (_Float16*)(ws + (4u << 20));             // 4 MB  [B][64][N]
    float*  qsq2 = (float*)(ws + (8u << 20));                // 128 KB [B][N]
    float*  ksq2 = (float*)(ws + (8u << 20) + (128u << 10)); // 128 KB

    proj_kernel<<<B_ * (N_ / 64), 256, 0, stream>>>(x, Wq, bq, Wk, bk, Wv, bv, sig,
                                                    qh, kh, vh, qsq2, ksq2);
    attn_kernel<<<B_ * (N_ / 64), 256, 0, stream>>>(x, qh, kh, vh, qsq2, ksq2, sig, out);
}

// Round 3
// 97.398 us; speedup vs baseline: 1.3520x; 1.0393x over previous
//
#include <hip/hip_runtime.h>
#include <hip/hip_bf16.h>

typedef __attribute__((ext_vector_type(4))) _Float16 f16x4;
typedef __attribute__((ext_vector_type(8))) _Float16 f16x8;
typedef __attribute__((ext_vector_type(4))) float f32x4;

#define B_ 8
#define N_ 4096
#define C_ 64
#define CQ_ 32
#define SPLIT 4
#define KEYS (N_ / SPLIT)
#define MB 64
#define NT (KEYS / MB)

#define L2E_ 1.4426950408889634f
#define LOG2L_ 0.5287663729448977f

// ---------------- projection kernel v3: 8 roles x 16 outputs, x via LDS ----------------
// grid: B*(N/64)=512 blocks, 512 threads (8 waves). wave=role, lane=pixel.
__global__ __launch_bounds__(512) void proj_kernel(
    const float* __restrict__ x,
    const float* __restrict__ Wq, const float* __restrict__ bq,
    const float* __restrict__ Wk, const float* __restrict__ bk,
    const float* __restrict__ Wv, const float* __restrict__ bv,
    const float* __restrict__ sigp,
    _Float16* __restrict__ qh, _Float16* __restrict__ kh,
    _Float16* __restrict__ vh,
    float* __restrict__ qsq2, float* __restrict__ ksq2)
{
    __shared__ float xs[64][64];   // [channel][pixel]
    __shared__ float sP[4][64];    // q/k norm partials
    const int t = threadIdx.x;
    const int role = __builtin_amdgcn_readfirstlane(t >> 6);
    const int l = t & 63;
    const int b = blockIdx.x >> 6;
    const int n0 = (blockIdx.x & 63) * 64;

    #pragma unroll
    for (int rep = 0; rep < 8; ++rep) {
        const int idx = rep * 512 + t;
        const int c = idx >> 6, pix = idx & 63;
        xs[c][pix] = x[((size_t)b * C_ + c) * N_ + n0 + pix];
    }
    __syncthreads();

    const float* Wr;
    const float* br;
    if (role < 2)      { Wr = Wq + role * 16 * 64;       br = bq + role * 16; }
    else if (role < 4) { Wr = Wk + (role - 2) * 16 * 64; br = bk + (role - 2) * 16; }
    else               { Wr = Wv + (role - 4) * 16 * 64; br = bv + (role - 4) * 16; }

    float acc[16];
    #pragma unroll
    for (int o = 0; o < 16; ++o) acc[o] = br[o];
    #pragma unroll
    for (int c0 = 0; c0 < 64; c0 += 8) {
        float xc[8];
        #pragma unroll
        for (int dc = 0; dc < 8; ++dc) xc[dc] = xs[c0 + dc][l];
        #pragma unroll
        for (int o = 0; o < 16; ++o) {
            #pragma unroll
            for (int dc = 0; dc < 8; ++dc)
                acc[o] = fmaf(Wr[o * 64 + c0 + dc], xc[dc], acc[o]);
        }
    }

    const int n = n0 + l;
    if (role < 4) {
        float s = 0.f;
        #pragma unroll
        for (int o = 0; o < 16; ++o) s = fmaf(acc[o], acc[o], s);
        sP[role][l] = s;
        _Float16* row = ((role < 2) ? qh : kh) + ((size_t)b * N_ + n) * CQ_ + (role & 1) * 16;
        #pragma unroll
        for (int j = 0; j < 2; ++j) {
            f16x8 h;
            #pragma unroll
            for (int e = 0; e < 8; ++e) h[e] = (_Float16)acc[j * 8 + e];
            *(f16x8*)(row + j * 8) = h;
        }
    } else {
        const int o0 = (role - 4) * 16;
        #pragma unroll
        for (int o = 0; o < 16; ++o)
            vh[((size_t)b * C_ + o0 + o) * N_ + n] = (_Float16)acc[o];
    }
    __syncthreads();
    const float sv = sigp[0];
    const float cdL = 0.7213475204444817f / (sv * sv);  // (log2e/2)/sigma^2
    if (t < 64)
        qsq2[(size_t)b * N_ + n0 + t] = (sP[0][t] + sP[1][t]) * cdL - LOG2L_;
    else if (t < 128)
        ksq2[(size_t)b * N_ + n0 + (t - 64)] = (sP[2][t - 64] + sP[3][t - 64]) * cdL;
}

// ---------------- fused RBF-attention v3: swapped QK^T, in-reg P, key-split ----------------
// grid: B*(N/64)*SPLIT = 2048 blocks, 256 threads (4 waves). Wave owns 16 queries,
// block owns KEYS=1024 keys. Partial O (fp16) + denom (f32) to workspace.
#define KPAD 40
#define VPAD 72
__global__ __launch_bounds__(256, 4) void attn_kernel(
    const _Float16* __restrict__ qh,
    const _Float16* __restrict__ kh,
    const _Float16* __restrict__ vh,
    const float* __restrict__ qsq2,
    const float* __restrict__ ksq2,
    const float* __restrict__ sigp,
    _Float16* __restrict__ opart,
    float* __restrict__ dpart)
{
    __shared__ __align__(16) _Float16 Ks[2][MB][KPAD];
    __shared__ __align__(16) _Float16 Vs[2][C_][VPAD];
    __shared__ float sKsq[2][MB];

    const int t = threadIdx.x;
    const int wid = t >> 6;
    const int l = t & 63;
    const int lg = l >> 4;
    const int lm = l & 15;

    const int split = blockIdx.x & (SPLIT - 1);
    const int qblk = (blockIdx.x >> 2) & 63;
    const int b = blockIdx.x >> 8;
    const int q0 = qblk * 64 + wid * 16;
    const int k0 = split * KEYS;

    const float sv = sigp[0];
    const float c1 = L2E_ / (sv * sv);

    // Q fragment: row=lm (query), channels 8*lg..8*lg+7
    const f16x8 qfrag = *(const f16x8*)(qh + ((size_t)b * N_ + q0 + lm) * CQ_ + 8 * lg);
    const float qs2 = qsq2[(size_t)b * N_ + q0 + lm];

    const int krow = t >> 2, kc4 = t & 3;
    const int vch = t >> 3, vc8 = t & 7;

    f32x4 kreg, vreg[2];
    float ksreg;
    auto LOADT = [&](int m0) {
        kreg = *(const f32x4*)(kh + ((size_t)b * N_ + k0 + m0 + krow) * CQ_ + kc4 * 8);
        #pragma unroll
        for (int rep = 0; rep < 2; ++rep)
            vreg[rep] = *(const f32x4*)(vh + ((size_t)b * C_ + rep * 32 + vch) * N_ + k0 + m0 + vc8 * 8);
        if (t < MB) ksreg = ksq2[(size_t)b * N_ + k0 + m0 + t];
    };
    auto WRITET = [&](int buf) {
        *(f32x4*)(&Ks[buf][krow][kc4 * 8]) = kreg;
        #pragma unroll
        for (int rep = 0; rep < 2; ++rep)
            *(f32x4*)(&Vs[buf][rep * 32 + vch][vc8 * 8]) = vreg[rep];
        if (t < MB) sKsq[buf][t] = ksreg;
    };

    f32x4 acc[4];
    #pragma unroll
    for (int i = 0; i < 4; ++i) acc[i] = (f32x4){0.f, 0.f, 0.f, 0.f};
    float denom = 0.f;

    LOADT(0);
    WRITET(0);
    __syncthreads();

    for (int it = 0; it < NT; ++it) {
        const int buf = it & 1;
        if (it + 1 < NT) LOADT((it + 1) * MB);

        // ---- S^T = K Q^T : lane holds S[key=tm*16+lg*4+r][query=lm] ----
        f32x4 S[MB / 16];
        #pragma unroll
        for (int tm = 0; tm < MB / 16; ++tm) {
            const f16x8 kf = *(const f16x8*)(&Ks[buf][tm * 16 + lm][8 * lg]);
            S[tm] = __builtin_amdgcn_mfma_f32_16x16x32_f16(
                kf, qfrag, (f32x4){0.f, 0.f, 0.f, 0.f}, 0, 0, 0);
        }
        // ---- w = exp2(exp2(S*c1 - qs2 - kq2)); denom; pack P into A-fragments ----
        f16x8 pa[2];
        #pragma unroll
        for (int tm = 0; tm < MB / 16; ++tm) {
            #pragma unroll
            for (int r = 0; r < 4; ++r) {
                const float kq2 = sKsq[buf][tm * 16 + lg * 4 + r];
                const float a = fmaf(S[tm][r], c1, -(qs2 + kq2));
                const float wg = __builtin_amdgcn_exp2f(__builtin_amdgcn_exp2f(a));
                denom += wg;
                pa[tm >> 1][(tm & 1) * 4 + r] = (_Float16)wg;
            }
        }
        // ---- O += P V : A=P in regs (keys at kappa(lg,e)), B=V loaded with same map ----
        #pragma unroll
        for (int j = 0; j < 2; ++j) {
            #pragma unroll
            for (int tc = 0; tc < 4; ++tc) {
                f16x8 vf;
                *(f16x4*)(&vf) = *(const f16x4*)(&Vs[buf][tc * 16 + lm][j * 32 + lg * 4]);
                *(((f16x4*)(&vf)) + 1) = *(const f16x4*)(&Vs[buf][tc * 16 + lm][j * 32 + 16 + lg * 4]);
                acc[tc] = __builtin_amdgcn_mfma_f32_16x16x32_f16(pa[j], vf, acc[tc], 0, 0, 0);
            }
        }
        if (it + 1 < NT) WRITET(buf ^ 1);
        __syncthreads();
    }

    // ---- denom: sum across lg groups (keys were split over lg) ----
    denom += __shfl_xor(denom, 16);
    denom += __shfl_xor(denom, 32);

    // ---- store partials: O layout D[row=query=lg*4+r][col=channel=tc*16+lm] ----
    const size_t obase = ((size_t)split * B_ + b) * N_ + q0;
    if (l < 16) dpart[obase + lm] = denom;
    #pragma unroll
    for (int tc = 0; tc < 4; ++tc) {
        #pragma unroll
        for (int r = 0; r < 4; ++r)
            opart[(obase + lg * 4 + r) * C_ + tc * 16 + lm] = (_Float16)acc[tc][r];
    }
}

// ---------------- combine kernel: sum partials, divide, add x ----------------
// grid: B*N*8/256 = 1024 blocks; thread handles 8 channels of one (b,n).
__global__ __launch_bounds__(256) void combine_kernel(
    const float* __restrict__ x,
    const _Float16* __restrict__ opart,
    const float* __restrict__ dpart,
    float* __restrict__ out)
{
    const int gid = blockIdx.x * 256 + threadIdx.x;
    const int c0 = (gid & 7) * 8;
    const int bn = gid >> 3;

    float den = 0.f;
    #pragma unroll
    for (int s = 0; s < SPLIT; ++s) den += dpart[(size_t)s * B_ * N_ + bn];
    const float rden = 1.0f / den;

    float o[8] = {0.f, 0.f, 0.f, 0.f, 0.f, 0.f, 0.f, 0.f};
    #pragma unroll
    for (int s = 0; s < SPLIT; ++s) {
        const f16x8 h = *(const f16x8*)(opart + (((size_t)s * B_ * N_ + bn) * C_ + c0));
        #pragma unroll
        for (int e = 0; e < 8; ++e) o[e] += (float)h[e];
    }

    const size_t base = (size_t)bn * C_ + c0;
    const f32x4 x0 = *(const f32x4*)(x + base);
    const f32x4 x1 = *(const f32x4*)(x + base + 4);
    f32x4 r0, r1;
    #pragma unroll
    for (int e = 0; e < 4; ++e) {
        r0[e] = x0[e] + o[e] * rden;
        r1[e] = x1[e] + o[e + 4] * rden;
    }
    *(f32x4*)(out + base) = r0;
    *(f32x4*)(out + base + 4) = r1;
}

extern "C" void kernel_launch(void* const* d_in, const int* in_sizes, int n_in,
                              void* d_out, int out_size, void* d_ws, size_t ws_size,
                              hipStream_t stream) {
    const float* x   = (const float*)d_in[0];
    const float* Wq  = (const float*)d_in[1];
    const float* bq  = (const float*)d_in[2];
    const float* Wk  = (const float*)d_in[3];
    const float* bk  = (const float*)d_in[4];
    const float* Wv  = (const float*)d_in[5];
    const float* bv  = (const float*)d_in[6];
    const float* sig = (const float*)d_in[7];
    float* out = (float*)d_out;

    char* ws = (char*)d_ws;
    _Float16* qh  = (_Float16*)(ws);                        // 2 MB   [B][N][32]
    _Float16* kh  = (_Float16*)(ws + (2u << 20));           // 2 MB   [B][N][32]
    _Float16* vh  = (_Float16*)(ws + (4u << 20));           // 4 MB   [B][64][N]
    float*  qsq2  = (float*)(ws + (8u << 20));              // 128 KB [B][N]
    float*  ksq2  = (float*)(ws + (8u << 20) + (128u << 10)); // 128 KB
    _Float16* opart = (_Float16*)(ws + (8u << 20) + (256u << 10)); // 16 MB [SPLIT][B][N][64]
    float*  dpart = (float*)(ws + (24u << 20) + (256u << 10));     // 512 KB [SPLIT][B][N]

    proj_kernel<<<B_ * (N_ / 64), 512, 0, stream>>>(x, Wq, bq, Wk, bk, Wv, bv, sig,
                                                    qh, kh, vh, qsq2, ksq2);
    attn_kernel<<<B_ * (N_ / 64) * SPLIT, 256, 0, stream>>>(qh, kh, vh, qsq2, ksq2, sig,
                                                            opart, dpart);
    combine_kernel<<<(B_ * N_ * 8) / 256, 256, 0, stream>>>(x, opart, dpart, out);
}

// Round 4
// 83.715 us; speedup vs baseline: 1.5730x; 1.1634x over previous
//
#include <hip/hip_runtime.h>
#include <hip/hip_bf16.h>

typedef __attribute__((ext_vector_type(4))) _Float16 f16x4;
typedef __attribute__((ext_vector_type(8))) _Float16 f16x8;
typedef __attribute__((ext_vector_type(4))) float f32x4;

#define B_ 8
#define N_ 4096
#define C_ 64
#define CQ_ 32
#define SPLIT 4
#define KEYS (N_ / SPLIT)
#define MB 64
#define NT (KEYS / MB)
#define QB 128   // queries per block (4 waves x 32)

#define L2E_ 1.4426950408889634f
#define LOG2L_ 0.5287663729448977f

// ---------------- projection kernel v4 ----------------
// grid: B*(N/64)=512 blocks, 512 threads (8 waves). wave=role, lane=pixel.
// Stores: qh = q * c1 (c1 = log2e/sigma^2), kh = k, vh = v (all fp16),
//         nqs = log2(log2e) - |q|^2*cdL,  nks = -|k|^2*cdL   (cdL = log2e/(2 sigma^2))
// so that attn computes a = S + nq + nk = log2(log2e) - log2e*dist/(2 sigma^2).
__global__ __launch_bounds__(512) void proj_kernel(
    const float* __restrict__ x,
    const float* __restrict__ Wq, const float* __restrict__ bq,
    const float* __restrict__ Wk, const float* __restrict__ bk,
    const float* __restrict__ Wv, const float* __restrict__ bv,
    const float* __restrict__ sigp,
    _Float16* __restrict__ qh, _Float16* __restrict__ kh,
    _Float16* __restrict__ vh,
    float* __restrict__ nqs, float* __restrict__ nks)
{
    __shared__ float xs[64][64];   // [channel][pixel]
    __shared__ float sP[4][64];    // q/k norm partials
    const int t = threadIdx.x;
    const int role = __builtin_amdgcn_readfirstlane(t >> 6);
    const int l = t & 63;
    const int b = blockIdx.x >> 6;
    const int n0 = (blockIdx.x & 63) * 64;

    #pragma unroll
    for (int rep = 0; rep < 8; ++rep) {
        const int idx = rep * 512 + t;
        const int c = idx >> 6, pix = idx & 63;
        xs[c][pix] = x[((size_t)b * C_ + c) * N_ + n0 + pix];
    }
    __syncthreads();

    const float* Wr;
    const float* br;
    if (role < 2)      { Wr = Wq + role * 16 * 64;       br = bq + role * 16; }
    else if (role < 4) { Wr = Wk + (role - 2) * 16 * 64; br = bk + (role - 2) * 16; }
    else               { Wr = Wv + (role - 4) * 16 * 64; br = bv + (role - 4) * 16; }

    float acc[16];
    #pragma unroll
    for (int o = 0; o < 16; ++o) acc[o] = br[o];
    #pragma unroll
    for (int c0 = 0; c0 < 64; c0 += 8) {
        float xc[8];
        #pragma unroll
        for (int dc = 0; dc < 8; ++dc) xc[dc] = xs[c0 + dc][l];
        #pragma unroll
        for (int o = 0; o < 16; ++o) {
            #pragma unroll
            for (int dc = 0; dc < 8; ++dc)
                acc[o] = fmaf(Wr[o * 64 + c0 + dc], xc[dc], acc[o]);
        }
    }

    const float sv = sigp[0];
    const float cdL = 0.7213475204444817f / (sv * sv);  // (log2e/2)/sigma^2
    const float c1 = 2.0f * cdL;                        // log2e/sigma^2

    const int n = n0 + l;
    if (role < 4) {
        float s = 0.f;
        #pragma unroll
        for (int o = 0; o < 16; ++o) s = fmaf(acc[o], acc[o], s);
        sP[role][l] = s;
        const bool isq = (role < 2);
        if (isq) {
            #pragma unroll
            for (int o = 0; o < 16; ++o) acc[o] *= c1;   // pre-scale q by c1
        }
        _Float16* row = (isq ? qh : kh) + ((size_t)b * N_ + n) * CQ_ + (role & 1) * 16;
        #pragma unroll
        for (int j = 0; j < 2; ++j) {
            f16x8 h;
            #pragma unroll
            for (int e = 0; e < 8; ++e) h[e] = (_Float16)acc[j * 8 + e];
            *(f16x8*)(row + j * 8) = h;
        }
    } else {
        const int o0 = (role - 4) * 16;
        #pragma unroll
        for (int o = 0; o < 16; ++o)
            vh[((size_t)b * C_ + o0 + o) * N_ + n] = (_Float16)acc[o];
    }
    __syncthreads();
    if (t < 64)
        nqs[(size_t)b * N_ + n0 + t] = LOG2L_ - (sP[0][t] + sP[1][t]) * cdL;
    else if (t < 128)
        nks[(size_t)b * N_ + n0 + (t - 64)] = -(sP[2][t - 64] + sP[3][t - 64]) * cdL;
}

// ---------------- fused RBF-attention v4 ----------------
// grid: B*(N/128)*SPLIT = 1024 blocks, 256 threads (4 waves). Wave owns 32 queries
// (two 16-row groups A/B), block owns KEYS=1024 keys. Denominator via ones-MFMA.
#define KPAD 40
#define VPAD 76
__global__ __launch_bounds__(256, 4) void attn_kernel(
    const _Float16* __restrict__ qh,
    const _Float16* __restrict__ kh,
    const _Float16* __restrict__ vh,
    const float* __restrict__ nqs,
    const float* __restrict__ nks,
    _Float16* __restrict__ opart,
    float* __restrict__ dpart)
{
    __shared__ __align__(16) _Float16 Ks[2][MB][KPAD];
    __shared__ __align__(16) _Float16 Vs[2][C_][VPAD];
    __shared__ float sK[2][MB];

    const int t = threadIdx.x;
    const int wid = t >> 6;
    const int l = t & 63;
    const int lg = l >> 4;
    const int lm = l & 15;

    const int split = blockIdx.x & (SPLIT - 1);
    const int qblk = (blockIdx.x >> 2) & 31;
    const int b = blockIdx.x >> 7;
    const int qbase = qblk * QB + wid * 32;
    const int k0 = split * KEYS;

    // Q fragments for the two 16-query groups; channels 8*lg..8*lg+7
    const f16x8 qfA = *(const f16x8*)(qh + ((size_t)b * N_ + qbase + lm) * CQ_ + 8 * lg);
    const f16x8 qfB = *(const f16x8*)(qh + ((size_t)b * N_ + qbase + 16 + lm) * CQ_ + 8 * lg);
    const float nqA = nqs[(size_t)b * N_ + qbase + lm];
    const float nqB = nqs[(size_t)b * N_ + qbase + 16 + lm];

    const int krow = t >> 2, kc4 = t & 3;
    const int vch = t >> 3, vc8 = t & 7;

    f32x4 kreg, vreg[2];
    float ksreg;
    auto LOADT = [&](int m0) {
        kreg = *(const f32x4*)(kh + ((size_t)b * N_ + k0 + m0 + krow) * CQ_ + kc4 * 8);
        #pragma unroll
        for (int rep = 0; rep < 2; ++rep)
            vreg[rep] = *(const f32x4*)(vh + ((size_t)b * C_ + rep * 32 + vch) * N_ + k0 + m0 + vc8 * 8);
        if (t < MB) ksreg = nks[(size_t)b * N_ + k0 + m0 + t];
    };
    auto WRITET = [&](int buf) {
        *(f32x4*)(&Ks[buf][krow][kc4 * 8]) = kreg;
        #pragma unroll
        for (int rep = 0; rep < 2; ++rep)
            *(f32x4*)(&Vs[buf][rep * 32 + vch][vc8 * 8]) = vreg[rep];
        if (t < MB) sK[buf][t] = ksreg;
    };

    f32x4 accA[4], accB[4], accdA, accdB;
    #pragma unroll
    for (int i = 0; i < 4; ++i) {
        accA[i] = (f32x4){0.f, 0.f, 0.f, 0.f};
        accB[i] = (f32x4){0.f, 0.f, 0.f, 0.f};
    }
    accdA = (f32x4){0.f, 0.f, 0.f, 0.f};
    accdB = (f32x4){0.f, 0.f, 0.f, 0.f};

    f16x8 ones;
    #pragma unroll
    for (int e = 0; e < 8; ++e) ones[e] = (_Float16)1.0f;

    LOADT(0);
    WRITET(0);
    __syncthreads();

    for (int it = 0; it < NT; ++it) {
        const int buf = it & 1;
        if (it + 1 < NT) LOADT((it + 1) * MB);

        #pragma unroll
        for (int j = 0; j < 2; ++j) {
            // ---- S^T = K Q^T for key-half j (32 keys) ----
            const f16x8 kf0 = *(const f16x8*)(&Ks[buf][j * 32 + lm][8 * lg]);
            const f16x8 kf1 = *(const f16x8*)(&Ks[buf][j * 32 + 16 + lm][8 * lg]);
            __builtin_amdgcn_s_setprio(1);
            f32x4 SA0 = __builtin_amdgcn_mfma_f32_16x16x32_f16(kf0, qfA, (f32x4){0.f,0.f,0.f,0.f}, 0, 0, 0);
            f32x4 SB0 = __builtin_amdgcn_mfma_f32_16x16x32_f16(kf0, qfB, (f32x4){0.f,0.f,0.f,0.f}, 0, 0, 0);
            f32x4 SA1 = __builtin_amdgcn_mfma_f32_16x16x32_f16(kf1, qfA, (f32x4){0.f,0.f,0.f,0.f}, 0, 0, 0);
            f32x4 SB1 = __builtin_amdgcn_mfma_f32_16x16x32_f16(kf1, qfB, (f32x4){0.f,0.f,0.f,0.f}, 0, 0, 0);
            __builtin_amdgcn_s_setprio(0);

            // ---- w = exp2(exp2(S + nq + nk)); pack P fragments ----
            f16x8 paA, paB;
            #pragma unroll
            for (int r = 0; r < 4; ++r) {
                const float nk0 = sK[buf][j * 32 + lg * 4 + r];
                const float nk1 = sK[buf][j * 32 + 16 + lg * 4 + r];
                paA[r]     = (_Float16)__builtin_amdgcn_exp2f(__builtin_amdgcn_exp2f(SA0[r] + nqA + nk0));
                paA[4 + r] = (_Float16)__builtin_amdgcn_exp2f(__builtin_amdgcn_exp2f(SA1[r] + nqA + nk1));
                paB[r]     = (_Float16)__builtin_amdgcn_exp2f(__builtin_amdgcn_exp2f(SB0[r] + nqB + nk0));
                paB[4 + r] = (_Float16)__builtin_amdgcn_exp2f(__builtin_amdgcn_exp2f(SB1[r] + nqB + nk1));
            }

            // ---- O += P V ; denom += P 1 ----
            __builtin_amdgcn_s_setprio(1);
            #pragma unroll
            for (int tc = 0; tc < 4; ++tc) {
                f16x8 vf;
                *(f16x4*)(&vf) = *(const f16x4*)(&Vs[buf][tc * 16 + lm][j * 32 + lg * 4]);
                *(((f16x4*)(&vf)) + 1) = *(const f16x4*)(&Vs[buf][tc * 16 + lm][j * 32 + 16 + lg * 4]);
                accA[tc] = __builtin_amdgcn_mfma_f32_16x16x32_f16(paA, vf, accA[tc], 0, 0, 0);
                accB[tc] = __builtin_amdgcn_mfma_f32_16x16x32_f16(paB, vf, accB[tc], 0, 0, 0);
            }
            accdA = __builtin_amdgcn_mfma_f32_16x16x32_f16(paA, ones, accdA, 0, 0, 0);
            accdB = __builtin_amdgcn_mfma_f32_16x16x32_f16(paB, ones, accdB, 0, 0, 0);
            __builtin_amdgcn_s_setprio(0);
        }
        if (it + 1 < NT) WRITET(buf ^ 1);
        __syncthreads();
    }

    // ---- store partials: D[query at lg*4+r][channel at lm] ----
    const size_t obA = ((size_t)split * B_ + b) * N_ + qbase;
    if (lm == 0) {
        #pragma unroll
        for (int r = 0; r < 4; ++r) {
            dpart[obA + lg * 4 + r] = accdA[r];
            dpart[obA + 16 + lg * 4 + r] = accdB[r];
        }
    }
    #pragma unroll
    for (int tc = 0; tc < 4; ++tc) {
        #pragma unroll
        for (int r = 0; r < 4; ++r) {
            opart[(obA + lg * 4 + r) * C_ + tc * 16 + lm] = (_Float16)accA[tc][r];
            opart[(obA + 16 + lg * 4 + r) * C_ + tc * 16 + lm] = (_Float16)accB[tc][r];
        }
    }
}

// ---------------- combine kernel: sum partials, divide, add x ----------------
__global__ __launch_bounds__(256) void combine_kernel(
    const float* __restrict__ x,
    const _Float16* __restrict__ opart,
    const float* __restrict__ dpart,
    float* __restrict__ out)
{
    const int gid = blockIdx.x * 256 + threadIdx.x;
    const int c0 = (gid & 7) * 8;
    const int bn = gid >> 3;

    float den = 0.f;
    #pragma unroll
    for (int s = 0; s < SPLIT; ++s) den += dpart[(size_t)s * B_ * N_ + bn];
    const float rden = 1.0f / den;

    float o[8] = {0.f, 0.f, 0.f, 0.f, 0.f, 0.f, 0.f, 0.f};
    #pragma unroll
    for (int s = 0; s < SPLIT; ++s) {
        const f16x8 h = *(const f16x8*)(opart + (((size_t)s * B_ * N_ + bn) * C_ + c0));
        #pragma unroll
        for (int e = 0; e < 8; ++e) o[e] += (float)h[e];
    }

    const size_t base = (size_t)bn * C_ + c0;
    const f32x4 x0 = *(const f32x4*)(x + base);
    const f32x4 x1 = *(const f32x4*)(x + base + 4);
    f32x4 r0, r1;
    #pragma unroll
    for (int e = 0; e < 4; ++e) {
        r0[e] = x0[e] + o[e] * rden;
        r1[e] = x1[e] + o[e + 4] * rden;
    }
    *(f32x4*)(out + base) = r0;
    *(f32x4*)(out + base + 4) = r1;
}

extern "C" void kernel_launch(void* const* d_in, const int* in_sizes, int n_in,
                              void* d_out, int out_size, void* d_ws, size_t ws_size,
                              hipStream_t stream) {
    const float* x   = (const float*)d_in[0];
    const float* Wq  = (const float*)d_in[1];
    const float* bq  = (const float*)d_in[2];
    const float* Wk  = (const float*)d_in[3];
    const float* bk  = (const float*)d_in[4];
    const float* Wv  = (const float*)d_in[5];
    const float* bv  = (const float*)d_in[6];
    const float* sig = (const float*)d_in[7];
    float* out = (float*)d_out;

    char* ws = (char*)d_ws;
    _Float16* qh  = (_Float16*)(ws);                          // 2 MB   [B][N][32]
    _Float16* kh  = (_Float16*)(ws + (2u << 20));             // 2 MB   [B][N][32]
    _Float16* vh  = (_Float16*)(ws + (4u << 20));             // 4 MB   [B][64][N]
    float*   nqs  = (float*)(ws + (8u << 20));                // 128 KB [B][N]
    float*   nks  = (float*)(ws + (8u << 20) + (128u << 10)); // 128 KB
    _Float16* opart = (_Float16*)(ws + (8u << 20) + (256u << 10)); // 16 MB [SPLIT][B][N][64]
    float*  dpart = (float*)(ws + (24u << 20) + (256u << 10));     // 512 KB [SPLIT][B][N]

    proj_kernel<<<B_ * (N_ / 64), 512, 0, stream>>>(x, Wq, bq, Wk, bk, Wv, bv, sig,
                                                    qh, kh, vh, nqs, nks);
    attn_kernel<<<B_ * (N_ / QB) * SPLIT, 256, 0, stream>>>(qh, kh, vh, nqs, nks,
                                                            opart, dpart);
    combine_kernel<<<(B_ * N_ * 8) / 256, 256, 0, stream>>>(x, opart, dpart, out);
}